// Round 1
// baseline (545.325 us; speedup 1.0000x reference)
//
#include <hip/hip_runtime.h>

// MRoPE: sections (32,32,32), ROTARY_DIM = HEAD_SIZE = 128 (no tail).
// cos_row[t,d] = cos[sec(d), t, d] with sec(d) = (d < 32) ? 0 : 1  (cos[2] unused)
// out[..., d]      = x[d]    * c[d] - x[d+64] * s[d]
// out[..., d + 64] = x[d+64] * c[d] + x[d]    * s[d]
//
// Work decomposition: thread = (token t, head h in [0,40), float4-pair jj in [0,16))
// heads 0..31 -> q, 32..39 -> k. 640 threads/token = exactly 10 waves/token,
// each wave entirely q or entirely k -> no divergence.

namespace {
constexpr int T_TOKENS = 16384;
constexpr int HALF     = 64;        // ROTARY_DIM / 2
constexpr int NQH      = 32;
constexpr int NKH      = 8;
constexpr int PAIRS_PER_HEAD = HALF / 4;              // 16 float4-pairs
constexpr int WORK_PER_TOKEN = (NQH + NKH) * PAIRS_PER_HEAD;  // 640
}

__global__ __launch_bounds__(256) void mrope_qk_kernel(
    const float* __restrict__ q,
    const float* __restrict__ k,
    const float* __restrict__ cosp,   // (3, T, 64)
    const float* __restrict__ sinp,   // (3, T, 64)
    float* __restrict__ out)          // q_out (T*4096) then k_out (T*1024)
{
    const int i = blockIdx.x * blockDim.x + threadIdx.x;
    const int total = T_TOKENS * WORK_PER_TOKEN;
    if (i >= total) return;

    const int t    = i / WORK_PER_TOKEN;
    const int rem  = i - t * WORK_PER_TOKEN;
    const int head = rem >> 4;     // 0..39
    const int d    = (rem & 15) << 2;  // 0,4,...,60

    // section select: d<32 -> cos[0]/sin[0], else cos[1]/sin[1]
    const size_t cs_off = (size_t)(d >= 32 ? 1 : 0) * ((size_t)T_TOKENS * HALF)
                        + (size_t)t * HALF + d;
    const float4 c = *(const float4*)(cosp + cs_off);
    const float4 s = *(const float4*)(sinp + cs_off);

    const float* src;
    float* dst;
    if (head < NQH) {
        const size_t off = (size_t)t * (NQH * 128) + (size_t)head * 128 + d;
        src = q + off;
        dst = out + off;
    } else {
        const size_t off = (size_t)t * (NKH * 128) + (size_t)(head - NQH) * 128 + d;
        src = k + off;
        dst = out + (size_t)T_TOKENS * NQH * 128 + off;
    }

    const float4 x1 = *(const float4*)(src);
    const float4 x2 = *(const float4*)(src + HALF);

    float4 o1, o2;
    o1.x = x1.x * c.x - x2.x * s.x;
    o1.y = x1.y * c.y - x2.y * s.y;
    o1.z = x1.z * c.z - x2.z * s.z;
    o1.w = x1.w * c.w - x2.w * s.w;
    o2.x = x2.x * c.x + x1.x * s.x;
    o2.y = x2.y * c.y + x1.y * s.y;
    o2.z = x2.z * c.z + x1.z * s.z;
    o2.w = x2.w * c.w + x1.w * s.w;

    *(float4*)(dst)        = o1;
    *(float4*)(dst + HALF) = o2;
}

extern "C" void kernel_launch(void* const* d_in, const int* in_sizes, int n_in,
                              void* d_out, int out_size, void* d_ws, size_t ws_size,
                              hipStream_t stream) {
    const float* q    = (const float*)d_in[0];
    const float* k    = (const float*)d_in[1];
    const float* cosp = (const float*)d_in[2];
    const float* sinp = (const float*)d_in[3];
    float* out = (float*)d_out;

    const int total  = T_TOKENS * WORK_PER_TOKEN;   // 10,485,760
    const int block  = 256;
    const int grid   = (total + block - 1) / block; // 40,960

    mrope_qk_kernel<<<grid, block, 0, stream>>>(q, k, cosp, sinp, out);
}